// Round 4
// baseline (95.663 us; speedup 1.0000x reference)
//
#include <hip/hip_runtime.h>

#define N_  128
#define C_  256
#define T_  48
#define V_  25

// Block = (n, sg2) where sg2 = group of 2 segments (6 frames, 150 floats/channel).
// Grid 1024 = 4 blocks/CU. Phase A computes frame means entirely in registers
// (7xfloat4 window per 25-float frame, select-masked edges). Phase B: tiny
// matvec chain in LDS. Phase D: re-read x (cache-hot) as float2, write out.
__global__ __launch_bounds__(512, 8) void k_fused3(
    const float* __restrict__ x,
    const float* __restrict__ wsq, const float* __restrict__ bsq,
    const float* __restrict__ gamma, const float* __restrict__ beta,
    const float* __restrict__ rmean, const float* __restrict__ rvar,
    const float* __restrict__ wc1, const float* __restrict__ bc1,
    const float* __restrict__ wex, const float* __restrict__ bex,
    float* __restrict__ out)
{
    __shared__ float xb[256 * 6];   // v-means [c][t]        6144 B
    __shared__ float part[192];     // squeeze partials [t][r][h]
    __shared__ float ybn[96];       // [t][r]
    __shared__ float y1[96];        // [t][s]
    __shared__ float mv[96];        // [t][r]
    __shared__ float gs[256 * 6];   // gate [c][t]           6144 B

    const int tid = threadIdx.x;
    const unsigned bid = blockIdx.x;
    const unsigned o   = (bid & 7u) * 128u + (bid >> 3);  // chunked XCD swizzle (1024%8==0)
    const unsigned n   = o >> 3;
    const unsigned sg2 = o & 7u;

    const size_t nbase = (size_t)n * 307200u;
    const unsigned soff = sg2 * 150u;                     // slice start within channel row

    // ---- Phase A: frame means in registers; no staging, no barrier until end ----
    #pragma unroll
    for (int k = 0; k < 3; ++k) {
        int f  = k * 512 + tid;            // 0..1535 = c*6 + tl
        int c  = f / 6;
        int tl = f - c * 6;
        int off = (int)soff + c * 1200 + tl * 25;   // float offset within n-slice
        int mis = off & 3;
        const float4* p = (const float4*)(x + nbase + (unsigned)(off - mis));
        float w[28];
        #pragma unroll
        for (int q = 0; q < 7; ++q) {
            float4 v = p[q];
            w[4*q] = v.x; w[4*q+1] = v.y; w[4*q+2] = v.z; w[4*q+3] = v.w;
        }
        float s = 0.f;
        #pragma unroll
        for (int i = 3; i <= 24; ++i) s += w[i];
        s += (mis == 0) ? w[0] : w[25];
        s += (mis <= 1) ? w[1] : w[26];
        s += (mis <= 2) ? w[2] : w[27];
        xb[f] = s * 0.04f;
    }
    __syncthreads();

    // ---- B1: squeeze partials: thread = (t, r, half) ----
    if (tid < 192) {
        int t = tid >> 5, rh = tid & 31, r = rh >> 1, h = rh & 1;
        const float* wrow = wsq + r * 256 + h * 128;
        float acc = 0.f;
        #pragma unroll 8
        for (int i = 0; i < 128; ++i) acc += xb[(h * 128 + i) * 6 + t] * wrow[i];
        part[tid] = acc;
    }
    __syncthreads();
    // ---- B1b: combine + BN ----
    if (tid < 96) {
        int t = tid >> 4, r = tid & 15;
        float acc = part[t * 32 + r * 2] + part[t * 32 + r * 2 + 1];
        float sc = gamma[r] * rsqrtf(rvar[r] + 1e-5f);
        ybn[t * 16 + r] = (acc + bsq[r]) * sc + (beta[r] - rmean[r] * sc);
    }
    __syncthreads();
    // ---- B2: conv1 ----
    if (tid < 96) {
        int t = tid >> 4, s = tid & 15;
        float acc = bc1[s];
        #pragma unroll
        for (int r = 0; r < 16; ++r) acc += ybn[t * 16 + r] * wc1[s * 16 + r];
        y1[t * 16 + s] = acc;
    }
    __syncthreads();
    // ---- B3: temporal diff (t%3==2 -> 0); 6 frames = 2 whole segments ----
    if (tid < 96) {
        int t = tid >> 4, r = tid & 15;
        mv[tid] = ((t % 3) < 2) ? (y1[(t + 1) * 16 + r] - ybn[t * 16 + r]) : 0.f;
    }
    __syncthreads();
    // ---- B4: expand + sigmoid: thread = (c, t-half) ----
    {
        int c = tid & 255, th = tid >> 8;
        float wexr[16];
        #pragma unroll
        for (int r = 0; r < 16; ++r) wexr[r] = wex[c * 16 + r];
        float be = bex[c];
        #pragma unroll
        for (int t = th * 3; t < th * 3 + 3; ++t) {
            float a = be;
            #pragma unroll
            for (int r = 0; r < 16; ++r) a += mv[t * 16 + r] * wexr[r];
            gs[c * 6 + t] = 1.f / (1.f + expf(-a));
        }
    }
    __syncthreads();

    // ---- Phase D: apply gate; float2 re-read (cache-hot) + float2 store ----
    const float* xg = x   + nbase + soff;
    float*       og = out + nbase + soff;
    #pragma unroll 4
    for (int it = 0; it < 38; ++it) {
        int j = it * 512 + tid;               // float2 index over 256ch x 150 floats
        if (j < 19200) {
            int c  = j / 75;
            int p2 = j - c * 75;
            int e0 = p2 * 2;                  // 0..148
            int t0 = (e0 * 41) >> 10;         // e0/25
            int t1 = ((e0 + 1) * 41) >> 10;
            float2 v = *(const float2*)(xg + (unsigned)(c * 1200 + e0));
            float2 ov;
            ov.x = v.x * gs[c * 6 + t0];
            ov.y = v.y * gs[c * 6 + t1];
            *(float2*)(og + (unsigned)(c * 1200 + e0)) = ov;
        }
    }
}

extern "C" void kernel_launch(void* const* d_in, const int* in_sizes, int n_in,
                              void* d_out, int out_size, void* d_ws, size_t ws_size,
                              hipStream_t stream) {
    const float* x     = (const float*)d_in[0];
    const float* wsq   = (const float*)d_in[1];
    const float* bsq   = (const float*)d_in[2];
    const float* gamma = (const float*)d_in[3];
    const float* beta  = (const float*)d_in[4];
    const float* rmean = (const float*)d_in[5];
    const float* rvar  = (const float*)d_in[6];
    const float* wc1   = (const float*)d_in[7];
    const float* bc1   = (const float*)d_in[8];
    const float* wex   = (const float*)d_in[9];
    const float* bex   = (const float*)d_in[10];

    k_fused3<<<1024, 512, 0, stream>>>(x, wsq, bsq, gamma, beta,
                                       rmean, rvar, wc1, bc1, wex, bex,
                                       (float*)d_out);
}

// Round 5
// 92.544 us; speedup vs baseline: 1.0337x; 1.0337x over previous
//
#include <hip/hip_runtime.h>

#define N_  128
#define C_  256
#define T_  48
#define V_  25

// Block = (n, sg) : sg = group of 4 segments = 12 frames, 300 floats/channel,
// 16B-aligned slice. Grid 512, block 512. Phase A: frame means computed in
// registers, two frames' loads issued back-to-back for MLP (needs VGPRs —
// launch_bounds(512,4) caps at 128, NOT 32 like R4's (512,8)).
__global__ __launch_bounds__(512, 4) void k_fused4(
    const float* __restrict__ x,
    const float* __restrict__ wsq, const float* __restrict__ bsq,
    const float* __restrict__ gamma, const float* __restrict__ beta,
    const float* __restrict__ rmean, const float* __restrict__ rvar,
    const float* __restrict__ wc1, const float* __restrict__ bc1,
    const float* __restrict__ wex, const float* __restrict__ bex,
    float* __restrict__ out)
{
    __shared__ float xb[256 * 12];  // v-means [c][t]   12 KB
    __shared__ float part[384];     // squeeze partials [t][r][h]
    __shared__ float ybn[192];      // [t][r]
    __shared__ float y1[192];       // [t][s]
    __shared__ float mv[192];       // [t][r]
    __shared__ float gs[256 * 12];  // gate [c][t]      12 KB

    const int tid = threadIdx.x;
    const unsigned bid = blockIdx.x;
    const unsigned o   = (bid & 7u) * 64u + (bid >> 3);   // chunked XCD swizzle (512%8==0)
    const unsigned n   = o >> 2;
    const unsigned sg  = o & 3u;

    const float* xg = x   + (size_t)n * 307200u + sg * 300u;   // + c*1200 + ...
    float*       og = out + (size_t)n * 307200u + sg * 300u;

    // ---- Phase A: 3072 frame means; 6 per thread, processed 2-at-a-time ----
    #pragma unroll
    for (int kk = 0; kk < 3; ++kk) {
        const int fA = (2 * kk) * 512 + tid;          // frame ids
        const int fB = (2 * kk + 1) * 512 + tid;
        const int cA = fA / 12, tA = fA - cA * 12;
        const int cB = fB / 12, tB = fB - cB * 12;
        const int misA = (tA * 25) & 3, misB = (tB * 25) & 3;
        const float4* pA = (const float4*)(xg + (unsigned)(cA * 1200 + tA * 25 - misA));
        const float4* pB = (const float4*)(xg + (unsigned)(cB * 1200 + tB * 25 - misB));
        float4 va[7], vb[7];
        #pragma unroll
        for (int q = 0; q < 7; ++q) va[q] = pA[q];    // 14 loads issued before
        #pragma unroll
        for (int q = 0; q < 7; ++q) vb[q] = pB[q];    // any consumption (MLP)
        float wa[28], wb[28];
        #pragma unroll
        for (int q = 0; q < 7; ++q) {
            wa[4*q] = va[q].x; wa[4*q+1] = va[q].y; wa[4*q+2] = va[q].z; wa[4*q+3] = va[q].w;
            wb[4*q] = vb[q].x; wb[4*q+1] = vb[q].y; wb[4*q+2] = vb[q].z; wb[4*q+3] = vb[q].w;
        }
        float sA = 0.f, sB = 0.f;
        #pragma unroll
        for (int i = 3; i <= 24; ++i) { sA += wa[i]; sB += wb[i]; }
        sA += (misA == 0) ? wa[0] : wa[25];
        sA += (misA <= 1) ? wa[1] : wa[26];
        sA += (misA <= 2) ? wa[2] : wa[27];
        sB += (misB == 0) ? wb[0] : wb[25];
        sB += (misB <= 1) ? wb[1] : wb[26];
        sB += (misB <= 2) ? wb[2] : wb[27];
        xb[fA] = sA * 0.04f;
        xb[fB] = sB * 0.04f;
    }
    __syncthreads();

    // ---- B1: squeeze partials: thread = (t, r, half) ----
    if (tid < 384) {
        int t = tid >> 5, rh = tid & 31, r = rh >> 1, h = rh & 1;
        const float* wrow = wsq + r * 256 + h * 128;
        float acc = 0.f;
        #pragma unroll 8
        for (int i = 0; i < 128; ++i) acc += xb[(h * 128 + i) * 12 + t] * wrow[i];
        part[tid] = acc;
    }
    __syncthreads();
    // ---- B1b: combine + BN ----
    if (tid < 192) {
        int t = tid >> 4, r = tid & 15;
        float acc = part[t * 32 + r * 2] + part[t * 32 + r * 2 + 1];
        float sc = gamma[r] * rsqrtf(rvar[r] + 1e-5f);
        ybn[t * 16 + r] = (acc + bsq[r]) * sc + (beta[r] - rmean[r] * sc);
    }
    __syncthreads();
    // ---- B2: conv1 ----
    if (tid < 192) {
        int t = tid >> 4, s = tid & 15;
        float acc = bc1[s];
        #pragma unroll
        for (int r = 0; r < 16; ++r) acc += ybn[t * 16 + r] * wc1[s * 16 + r];
        y1[t * 16 + s] = acc;
    }
    __syncthreads();
    // ---- B3: temporal diff (t%3==2 -> 0); 12 frames = 4 whole segments ----
    if (tid < 192) {
        int t = tid >> 4, r = tid & 15;
        mv[tid] = ((t % 3) < 2) ? (y1[(t + 1) * 16 + r] - ybn[t * 16 + r]) : 0.f;
    }
    __syncthreads();
    // ---- B4: expand + sigmoid: thread = (c, t-half), 6 frames each ----
    {
        int c = tid & 255, th = tid >> 8;
        float wexr[16];
        #pragma unroll
        for (int r = 0; r < 16; ++r) wexr[r] = wex[c * 16 + r];
        float be = bex[c];
        #pragma unroll
        for (int t = th * 6; t < th * 6 + 6; ++t) {
            float a = be;
            #pragma unroll
            for (int r = 0; r < 16; ++r) a += mv[t * 16 + r] * wexr[r];
            gs[c * 12 + t] = 1.f / (1.f + expf(-a));
        }
    }
    __syncthreads();

    // ---- Phase D: apply gate; float4 re-read (L3-hot) + aligned float4 store ----
    #pragma unroll 4
    for (int it = 0; it < 38; ++it) {
        int j = it * 512 + tid;                // float4 index, 0..19199
        if (j < 19200) {
            int c = j / 75, pos = j - c * 75;
            const float4 v = *(const float4*)(xg + (unsigned)(c * 1200 + pos * 4));
            int p4  = pos * 4;
            int t0  = (p4 * 41) >> 10;         // p4/25, exact for p4<1024
            int t3  = ((p4 + 3) * 41) >> 10;
            int rem = p4 - t0 * 25;
            float g0 = gs[c * 12 + t0];
            float g3 = gs[c * 12 + t3];
            float4 ov;
            ov.x = v.x * g0;
            ov.y = v.y * ((rem + 1 < 25) ? g0 : g3);
            ov.z = v.z * ((rem + 2 < 25) ? g0 : g3);
            ov.w = v.w * ((rem + 3 < 25) ? g0 : g3);
            *(float4*)(og + (unsigned)(c * 1200 + pos * 4)) = ov;
        }
    }
}

extern "C" void kernel_launch(void* const* d_in, const int* in_sizes, int n_in,
                              void* d_out, int out_size, void* d_ws, size_t ws_size,
                              hipStream_t stream) {
    const float* x     = (const float*)d_in[0];
    const float* wsq   = (const float*)d_in[1];
    const float* bsq   = (const float*)d_in[2];
    const float* gamma = (const float*)d_in[3];
    const float* beta  = (const float*)d_in[4];
    const float* rmean = (const float*)d_in[5];
    const float* rvar  = (const float*)d_in[6];
    const float* wc1   = (const float*)d_in[7];
    const float* bc1   = (const float*)d_in[8];
    const float* wex   = (const float*)d_in[9];
    const float* bex   = (const float*)d_in[10];

    k_fused4<<<512, 512, 0, stream>>>(x, wsq, bsq, gamma, beta,
                                      rmean, rvar, wc1, bc1, wex, bex,
                                      (float*)d_out);
}

// Round 6
// 89.265 us; speedup vs baseline: 1.0717x; 1.0367x over previous
//
#include <hip/hip_runtime.h>

#define N_  128
#define C_  256
#define T_  48
#define V_  25

__device__ __forceinline__ float b2f(unsigned short u) {
    union { float f; unsigned i; } c; c.i = ((unsigned)u) << 16; return c.f;
}
__device__ __forceinline__ unsigned short f2b(float f) {
    union { float f; unsigned i; } c; c.f = f;
    unsigned r = c.i + 0x7fffu + ((c.i >> 16) & 1u);   // RNE (matches __float2bfloat16 for normals)
    return (unsigned short)(r >> 16);
}

// Block = (n, seg): 256 ch x 75 floats (3 frames), fully resident in LDS as bf16.
// x read ONCE (coalesced: 18 aligned float4 + 3 edge scalars per row), gate math
// in-block, apply from LDS, coalesced write. Grid 2048 = 2.7 residency rounds
// at 3 blocks/CU -> cross-block phase overlap keeps HBM busy.
__global__ __launch_bounds__(256, 3) void k_fused5(
    const float* __restrict__ x,
    const float* __restrict__ wsq, const float* __restrict__ bsq,
    const float* __restrict__ gamma, const float* __restrict__ beta,
    const float* __restrict__ rmean, const float* __restrict__ rvar,
    const float* __restrict__ wc1, const float* __restrict__ bc1,
    const float* __restrict__ wex, const float* __restrict__ bex,
    float* __restrict__ out)
{
    __shared__ unsigned short xs[256 * 78]; // bf16 tile, row stride 78 (pad: bank spread)
    __shared__ float xb[256 * 3];           // v-means [c][t]
    __shared__ float ybn[48];               // [t][r]
    __shared__ float y1[48];                // [t][s]
    __shared__ float mv[48];                // [t][r]
    __shared__ float gs[256 * 3];           // gate [c][t]

    const int tid = threadIdx.x;
    const unsigned bid = blockIdx.x;
    // chunked XCD swizzle: xcd = bid%8 owns o in [xcd*256, xcd*256+256)
    const unsigned o   = (bid & 7u) * 256u + (bid >> 3);
    const unsigned n   = o >> 4;
    const unsigned seg = o & 15u;

    const size_t nbase = (size_t)n * 307200u;
    const int a = (int)((seg * 75u) & 3u);      // row misalignment (floats)
    const int h = (4 - a) & 3;                  // head floats before aligned region
    const float* rowx = x   + nbase + seg * 75u;   // + c*1200
    float*       rowo = out + nbase + seg * 75u;

    // ---- Phase A: coalesced read -> bf16 LDS ----
    // f4 part: row layout in LDS is left-shifted by h: slot m-h for m in [h, h+72)
    #pragma unroll
    for (int it = 0; it < 18; ++it) {
        int j = it * 256 + tid;                 // 0..4607
        int c = j / 18, k = j - c * 18;
        const float4 v = *(const float4*)(rowx + (unsigned)(c * 1200 + h + k * 4));
        unsigned p0 = (unsigned)f2b(v.x) | ((unsigned)f2b(v.y) << 16);
        unsigned p1 = (unsigned)f2b(v.z) | ((unsigned)f2b(v.w) << 16);
        unsigned s  = (unsigned)(c * 78 + k * 4);
        *(unsigned*)&xs[s]     = p0;
        *(unsigned*)&xs[s + 2] = p1;
    }
    // edge part: 3 leftover floats/row (head [0,h) and tail [h+72,75)) -> slots 72..74
    {
        int j = tid;                            // 768 = 256*3, 3 iters
        #pragma unroll
        for (int it = 0; it < 3; ++it, j += 256) {
            int c = j / 3, e = j - c * 3;
            int m = (e < h) ? e : e + 72;
            xs[c * 78 + 72 + e] = f2b(rowx[(unsigned)(c * 1200 + m)]);
        }
    }
    // prefetch expand weights while waiting
    float wexr[16];
    #pragma unroll
    for (int r = 0; r < 16; ++r) wexr[r] = wex[tid * 16 + r];
    const float bexr = bex[tid];
    __syncthreads();

    // ---- v-means: thread = channel ----
    {
        const int c = tid;
        float st[3] = {0.f, 0.f, 0.f};
        #pragma unroll
        for (int t = 0; t < 3; ++t) {
            #pragma unroll
            for (int v = 0; v < 25; ++v) {
                int m = t * 25 + v;
                int s = (m >= h && m < h + 72) ? (m - h) : ((m < h) ? 72 + m : m);
                st[t] += b2f(xs[c * 78 + s]);
            }
        }
        xb[c * 3 + 0] = st[0] * 0.04f;
        xb[c * 3 + 1] = st[1] * 0.04f;
        xb[c * 3 + 2] = st[2] * 0.04f;
    }
    __syncthreads();

    // ---- B1: squeeze + BN (48 threads) ----
    if (tid < 48) {
        const int tt = tid >> 4, r = tid & 15;
        float acc = 0.f;
        for (int c = 0; c < 256; ++c) acc += xb[c * 3 + tt] * wsq[r * 256 + c];
        float sc = gamma[r] * rsqrtf(rvar[r] + 1e-5f);
        ybn[tt * 16 + r] = (acc + bsq[r]) * sc + (beta[r] - rmean[r] * sc);
    }
    __syncthreads();
    // ---- B2: conv1 (48 threads) ----
    if (tid < 48) {
        const int tt = tid >> 4, s = tid & 15;
        float acc = bc1[s];
        #pragma unroll
        for (int r = 0; r < 16; ++r) acc += ybn[tt * 16 + r] * wc1[s * 16 + r];
        y1[tt * 16 + s] = acc;
    }
    __syncthreads();
    // ---- B3: temporal diff ----
    if (tid < 48) {
        const int tt = tid >> 4, r = tid & 15;
        mv[tid] = (tt < 2) ? (y1[(tt + 1) * 16 + r] - ybn[tt * 16 + r]) : 0.f;
    }
    __syncthreads();
    // ---- B4: expand + sigmoid: thread = channel ----
    {
        #pragma unroll
        for (int t = 0; t < 3; ++t) {
            float acc = bexr;
            #pragma unroll
            for (int r = 0; r < 16; ++r) acc += mv[t * 16 + r] * wexr[r];
            gs[tid * 3 + t] = 1.f / (1.f + expf(-acc));
        }
    }
    __syncthreads();

    // ---- Phase D: apply from LDS, coalesced write ----
    #pragma unroll
    for (int it = 0; it < 18; ++it) {
        int j = it * 256 + tid;
        int c = j / 18, k = j - c * 18;
        unsigned s = (unsigned)(c * 78 + k * 4);
        unsigned q0 = *(const unsigned*)&xs[s];
        unsigned q1 = *(const unsigned*)&xs[s + 2];
        int m0  = h + k * 4;
        int t0  = (m0 * 41) >> 10;              // m0/25
        int rem = m0 - t0 * 25;
        float g0 = gs[c * 3 + t0];
        float g3 = gs[c * 3 + (((m0 + 3) * 41) >> 10)];
        float4 ov;
        ov.x = b2f((unsigned short)(q0 & 0xffffu)) * g0;
        ov.y = b2f((unsigned short)(q0 >> 16)) * ((rem + 1 < 25) ? g0 : g3);
        ov.z = b2f((unsigned short)(q1 & 0xffffu)) * ((rem + 2 < 25) ? g0 : g3);
        ov.w = b2f((unsigned short)(q1 >> 16)) * ((rem + 3 < 25) ? g0 : g3);
        *(float4*)(rowo + (unsigned)(c * 1200 + h + k * 4)) = ov;
    }
    {
        int j = tid;
        #pragma unroll
        for (int it = 0; it < 3; ++it, j += 256) {
            int c = j / 3, e = j - c * 3;
            int m = (e < h) ? e : e + 72;
            int t = (m * 41) >> 10;
            rowo[(unsigned)(c * 1200 + m)] = b2f(xs[c * 78 + 72 + e]) * gs[c * 3 + t];
        }
    }
}

extern "C" void kernel_launch(void* const* d_in, const int* in_sizes, int n_in,
                              void* d_out, int out_size, void* d_ws, size_t ws_size,
                              hipStream_t stream) {
    const float* x     = (const float*)d_in[0];
    const float* wsq   = (const float*)d_in[1];
    const float* bsq   = (const float*)d_in[2];
    const float* gamma = (const float*)d_in[3];
    const float* beta  = (const float*)d_in[4];
    const float* rmean = (const float*)d_in[5];
    const float* rvar  = (const float*)d_in[6];
    const float* wc1   = (const float*)d_in[7];
    const float* bc1   = (const float*)d_in[8];
    const float* wex   = (const float*)d_in[9];
    const float* bex   = (const float*)d_in[10];

    k_fused5<<<2048, 256, 0, stream>>>(x, wsq, bsq, gamma, beta,
                                       rmean, rvar, wc1, bc1, wex, bex,
                                       (float*)d_out);
}